// Round 11
// baseline (160.740 us; speedup 1.0000x reference)
//
#include <hip/hip_runtime.h>
#include <math.h>

// B=8192, D=128, NUM_CLASSES=512, MARGIN=0.2
#define BATCH 8192
#define DIM 128
#define MARGIN_F 0.2f
#define NCLS 512
#define MAXM 64          // max members per class staged (expected ~16)

#define NCHUNK 16        // column chunks for mining
#define CHW 512          // cols per chunk
#define ST 64            // cols per block step (4 waves as 2x2, wave tile 32x32)
#define NT (CHW / ST)    // steps per chunk = 8
#define NRB (BATCH / 64) // 128 row blocks
#define NBLK2 (NRB * NCHUNK)   // 2048 mining blocks -> 8 blocks/CU

typedef _Float16 f16x8 __attribute__((ext_vector_type(8)));
typedef float    f32x4 __attribute__((ext_vector_type(4)));

// Fragment-packed layout: for 16-index group ct (0..511), K-step kc (0..3), lane l:
//   F[ct*4096 + kc*1024 + l*16] = fp16x8 { e_hat[idx = ct*16 + (l&15)][k = kc*32 + (l>>4)*8 + j] }
// One coalesced 1KB wave-load per (ct,kc) = one MFMA fragment (A and B identically).

// ================= K1: fused normalize/frag-pack (blocks 0..127) + per-class d_ap (blocks 128..639) =================
__global__ __launch_bounds__(1024) void tl_prep(const float* __restrict__ emb,
                                                const int* __restrict__ labels,
                                                unsigned short* __restrict__ F,
                                                float* __restrict__ dapA) {
    __shared__ float Lrow[MAXM][DIM + 4];
    __shared__ unsigned int minU[MAXM];
    __shared__ float linv[MAXM];
    __shared__ int   lidx[MAXM];
    __shared__ int   lcnt;

    const int blk = blockIdx.x;
    const int tid = threadIdx.x;

    if (blk < BATCH / 64) {
        // ---- prep path: 64 rows/block, 16 threads/row (seg = k/8), fragment-order 16B stores ----
        int rloc = tid >> 4;
        int seg  = tid & 15;           // 8-element k-segment 0..15
        int row  = blk * 64 + rloc;
        const float4* p = reinterpret_cast<const float4*>(emb + (size_t)row * DIM);
        float4 a = p[seg * 2], b = p[seg * 2 + 1];
        float ss = a.x*a.x + a.y*a.y + a.z*a.z + a.w*a.w
                 + b.x*b.x + b.y*b.y + b.z*b.z + b.w*b.w;
#pragma unroll
        for (int o = 1; o < 16; o <<= 1) ss += __shfl_xor(ss, o);
        float inv = 1.0f / fmaxf(sqrtf(ss), 1e-12f);
        f16x8 h;
        h[0]=(_Float16)(a.x*inv); h[1]=(_Float16)(a.y*inv);
        h[2]=(_Float16)(a.z*inv); h[3]=(_Float16)(a.w*inv);
        h[4]=(_Float16)(b.x*inv); h[5]=(_Float16)(b.y*inv);
        h[6]=(_Float16)(b.z*inv); h[7]=(_Float16)(b.w*inv);
        int kc = seg >> 2, g = seg & 3;
        size_t off = (size_t)(row >> 4) * 4096 + kc * 1024 + g * 256 + (row & 15) * 16;
        *reinterpret_cast<f16x8*>((char*)F + off) = h;
        return;
    }

    // ---- class path: hardest positive for every member of class c ----
    const int c = blk - BATCH / 64;
    if (tid == 0) lcnt = 0;
    if (tid < MAXM) minU[tid] = 0xFFFFFFFFu;
    __syncthreads();

#pragma unroll
    for (int k = 0; k < BATCH / 1024; ++k) {      // 8 iterations
        int idx = tid + k * 1024;
        if (labels[idx] == c) {
            int p = atomicAdd(&lcnt, 1);
            if (p < MAXM) lidx[p] = idx;
        }
    }
    __syncthreads();
    const int cnt = min(lcnt, MAXM);

    // stage member rows (16 threads per member: 2 float4 each) + inverse norms
    {
        int m = tid >> 4, q = tid & 15;
        float ss = 0.0f;
        if (m < cnt) {
            const float4* src = reinterpret_cast<const float4*>(emb + (size_t)lidx[m] * DIM) + q * 2;
            float4 v0 = src[0], v1 = src[1];
            *reinterpret_cast<float4*>(&Lrow[m][q * 8])     = v0;
            *reinterpret_cast<float4*>(&Lrow[m][q * 8 + 4]) = v1;
            ss = v0.x*v0.x + v0.y*v0.y + v0.z*v0.z + v0.w*v0.w
               + v1.x*v1.x + v1.y*v1.y + v1.z*v1.z + v1.w*v1.w;
        }
#pragma unroll
        for (int o = 1; o < 16; o <<= 1) ss += __shfl_xor(ss, o);
        if (m < cnt && q == 0) linv[m] = 1.0f / fmaxf(sqrtf(ss), 1e-12f);
    }
    __syncthreads();

    // all-pairs min dot per member (min order-invariant -> deterministic)
    const int P = cnt * cnt;
    for (int p = tid; p < P; p += 1024) {
        int i = p / cnt, j = p - i * cnt;
        if (i != j) {
            const float4* ra = reinterpret_cast<const float4*>(&Lrow[i][0]);
            const float4* rb = reinterpret_cast<const float4*>(&Lrow[j][0]);
            float acc = 0.0f;
#pragma unroll
            for (int u8 = 0; u8 < 32; ++u8) {
                float4 a = ra[u8], b = rb[u8];
                acc += a.x*b.x + a.y*b.y + a.z*b.z + a.w*b.w;
            }
            float dm = acc * linv[i] * linv[j];
            unsigned u   = __float_as_uint(dm);
            unsigned key = (u >> 31) ? ~u : (u | 0x80000000u);
            atomicMin(&minU[i], key);
        }
    }
    __syncthreads();

    if (tid < cnt) {
        float dap = -INFINITY;
        if (cnt >= 2) {
            unsigned key = minU[tid];
            unsigned u   = (key & 0x80000000u) ? (key & 0x7FFFFFFFu) : ~key;
            float md = __uint_as_float(u);
            dap = fmaxf(1.0f - md, 0.0f);
        }
        dapA[lidx[tid]] = dap;
    }
}

// ================= K2: barrier-free fragment-stream MFMA mining =================
__global__ __launch_bounds__(256, 8) void tl_mine(const unsigned short* __restrict__ Fm,
                                                  const int* __restrict__ labels,
                                                  const float* __restrict__ dapA,
                                                  float* __restrict__ part) {
    __shared__ int   Ls[CHW];        // 2 KB chunk labels
    __shared__ float mkS[2][64];

    const int tid = threadIdx.x;
    const int l   = tid & 63;
    const int wid = tid >> 6;
    const int wr  = wid >> 1, wc = wid & 1;   // 2x2 wave grid; wave tile 32 rows x 32 cols
    const int rb  = blockIdx.x >> 4;
    const int ch  = blockIdx.x & (NCHUNK - 1);
    const int rowBase = rb * 64;
    const int colBase = ch * CHW;
    const char* F = (const char*)Fm;

    const int lo   = l & 15;
    const int kgrp = l >> 4;

    // stage chunk labels once: 512 ints = 2 KB, waves 0 and 1 (wave-uniform LDS dest)
    if (wid < 2)
        __builtin_amdgcn_global_load_lds(
            (const __attribute__((address_space(1))) unsigned int*)(labels + colBase + wid * 256 + l * 4),
            (__attribute__((address_space(3))) unsigned int*)((char*)Ls + wid * 1024),
            16, 0, 0);

    // A fragments: 2 row-groups x 4 kc, each one coalesced 1KB wave-load
    const int ctA = (rowBase >> 4) + wr * 2;
    f16x8 af[2][4];
#pragma unroll
    for (int rf = 0; rf < 2; ++rf)
#pragma unroll
        for (int kc = 0; kc < 4; ++kc)
            af[rf][kc] = *reinterpret_cast<const f16x8*>(
                F + (size_t)(ctA + rf) * 4096 + kc * 1024 + l * 16);

    // per-row mining state (C/D: col=lane&15, row=(lane>>4)*4+reg)
    float wCen[8]; int la[8]; float mk[8];
#pragma unroll
    for (int rf = 0; rf < 2; ++rf)
#pragma unroll
        for (int i = 0; i < 4; ++i) {
            int r = rowBase + wr * 32 + rf * 16 + kgrp * 4 + i;
            float draw = dapA[r];
            float ds   = (draw > -1e30f) ? draw : 0.0f;
            wCen[rf * 4 + i] = (1.0f - ds) - 0.5f * MARGIN_F;
            la[rf * 4 + i]   = labels[r];
            mk[rf * 4 + i]   = -INFINITY;
        }
    __syncthreads();   // labels staged; only barrier before the part-write

    const int ctC0 = (colBase >> 4) + wc * 2;   // first col-group for this wave at step 0
    for (int t = 0; t < NT; ++t) {
        // 8 coalesced fragment loads (independent -> deep pipelining via TLP/ILP)
        f16x8 bf[2][4];
#pragma unroll
        for (int cf = 0; cf < 2; ++cf)
#pragma unroll
            for (int kc = 0; kc < 4; ++kc)
                bf[cf][kc] = *reinterpret_cast<const f16x8*>(
                    F + (size_t)(ctC0 + t * 4 + cf) * 4096 + kc * 1024 + l * 16);

        int lbB[2];
#pragma unroll
        for (int cf = 0; cf < 2; ++cf)
            lbB[cf] = Ls[t * ST + wc * 32 + cf * 16 + lo];

        f32x4 acc[2][2];
#pragma unroll
        for (int rf = 0; rf < 2; ++rf)
#pragma unroll
            for (int cf = 0; cf < 2; ++cf) {
                acc[rf][cf][0] = 0.0f; acc[rf][cf][1] = 0.0f;
                acc[rf][cf][2] = 0.0f; acc[rf][cf][3] = 0.0f;
            }

#pragma unroll
        for (int kc = 0; kc < 4; ++kc)
#pragma unroll
            for (int rf = 0; rf < 2; ++rf)
#pragma unroll
                for (int cf = 0; cf < 2; ++cf)
                    acc[rf][cf] = __builtin_amdgcn_mfma_f32_16x16x32_f16(
                        af[rf][kc], bf[cf][kc], acc[rf][cf], 0, 0, 0);

        // fused mining epilogue (dot space, single key)
#pragma unroll
        for (int rf = 0; rf < 2; ++rf)
#pragma unroll
            for (int i = 0; i < 4; ++i) {
                int ri = rf * 4 + i;
                float cen = wCen[ri];
                int   lr  = la[ri];
                float d0  = acc[rf][0][i];
                float d1  = acc[rf][1][i];
                bool  w0  = fabsf(d0 - cen) < (0.5f * MARGIN_F);
                bool  w1  = fabsf(d1 - cen) < (0.5f * MARGIN_F);
                float k0  = w0 ? d0 : d0 - 4.0f;
                float k1  = w1 ? d1 : d1 - 4.0f;
                k0 = (lbB[0] != lr) ? k0 : -INFINITY;
                k1 = (lbB[1] != lr) ? k1 : -INFINITY;
                mk[ri] = fmaxf(mk[ri], fmaxf(k0, k1));   // -> v_max3_f32
            }
    }

    // reduce across the 16 lanes sharing rows (lane bits 0..3)
#pragma unroll
    for (int m = 1; m < 16; m <<= 1)
#pragma unroll
        for (int r8 = 0; r8 < 8; ++r8)
            mk[r8] = fmaxf(mk[r8], __shfl_xor(mk[r8], m));
    if (lo == 0) {
#pragma unroll
        for (int rf = 0; rf < 2; ++rf)
#pragma unroll
            for (int i = 0; i < 4; ++i)
                mkS[wc][wr * 32 + rf * 16 + kgrp * 4 + i] = mk[rf * 4 + i];
    }
    __syncthreads();
    if (tid < 64)
        part[(size_t)ch * BATCH + rowBase + tid] = fmaxf(mkS[0][tid], mkS[1][tid]);
}

// ================= K3: finalize (separate launch; stream order provides visibility) =================
__global__ __launch_bounds__(1024) void tl_fin(const float* __restrict__ dapA,
                                               const float* __restrict__ part,
                                               float* __restrict__ out) {
    int tid = threadIdx.x;
    float s = 0.0f, cc = 0.0f;
    for (int r = tid; r < BATCH; r += 1024) {
        float draw = dapA[r];
        float mkv  = part[r];
#pragma unroll
        for (int chh = 1; chh < NCHUNK; ++chh)
            mkv = fmaxf(mkv, part[(size_t)chh * BATCH + r]);
        bool hasPos = draw > -1e30f;
        bool hasNeg = mkv  > -1e30f;
        float dapv  = hasPos ? draw : 0.0f;
        bool  semi  = mkv > -2.0f;                 // window keys > -1.3; shifted keys < -2.9
        float dotAn = semi ? mkv : mkv + 4.0f;
        float dan   = fmaxf(1.0f - dotAn, 0.0f);
        if (hasPos && hasNeg) {
            s  += fmaxf(dapv - dan + MARGIN_F, 0.0f);
            cc += 1.0f;
        }
    }
#pragma unroll
    for (int o = 32; o > 0; o >>= 1) { s += __shfl_xor(s, o); cc += __shfl_xor(cc, o); }
    __shared__ float ssum[16], scnt[16];
    int w = tid >> 6;
    if ((tid & 63) == 0) { ssum[w] = s; scnt[w] = cc; }
    __syncthreads();
    if (tid == 0) {
        float S = 0.0f, C = 0.0f;
#pragma unroll
        for (int i = 0; i < 16; ++i) { S += ssum[i]; C += scnt[i]; }
        out[0] = S / fmaxf(C, 1.0f);
    }
}

extern "C" void kernel_launch(void* const* d_in, const int* in_sizes, int n_in,
                              void* d_out, int out_size, void* d_ws, size_t ws_size,
                              hipStream_t stream) {
    const float* emb    = (const float*)d_in[0];
    const int*   labels = (const int*)d_in[1];
    float*       out    = (float*)d_out;

    char* ws = (char*)d_ws;
    unsigned short* F    = (unsigned short*)(ws);                          // 2 MB fragment-packed
    float*        dapA   = (float*)(ws + 2 * 1024 * 1024);                 // 32 KB
    float*        part   = (float*)(ws + 2 * 1024 * 1024 + 64 * 1024);     // 512 KB

    tl_prep<<<BATCH / 64 + NCLS, 1024, 0, stream>>>(emb, labels, F, dapA);
    tl_mine<<<NBLK2, 256, 0, stream>>>(F, labels, dapA, part);
    tl_fin <<<1, 1024, 0, stream>>>(dapA, part, out);
}

// Round 12
// 44.048 us; speedup vs baseline: 3.6492x; 3.6492x over previous
//
#include <hip/hip_runtime.h>
#include <math.h>

// B=8192, D=128, NUM_CLASSES=512, MARGIN=0.2
#define BATCH 8192
#define DIM 128
#define MARGIN_F 0.2f
#define NCLS 512
#define MAXM 64          // max members per class staged (expected ~16)

#define NCHUNK 8         // column chunks for mining
#define CHW 1024         // cols per chunk
#define ST 64            // cols per block step (4 waves as 2x2, wave tile 32x32)
#define NT (CHW / ST)    // steps per chunk = 16
#define NRB (BATCH / 64) // 128 row blocks
#define NBLK2 (NRB * NCHUNK)   // 1024 mining blocks -> 4 blocks/CU

typedef _Float16 f16x8 __attribute__((ext_vector_type(8)));
typedef float    f32x4 __attribute__((ext_vector_type(4)));

// Fragment-packed layout: for 16-index group ct (0..511), K-step kc (0..3), lane l:
//   F[ct*4096 + kc*1024 + l*16] = fp16x8 { e_hat[idx = ct*16 + (l&15)][k = kc*32 + (l>>4)*8 + j] }
// One coalesced 1KB wave-load per (ct,kc) = one MFMA fragment (A and B identically).

// ================= K1: fused normalize/frag-pack (blocks 0..127) + per-class d_ap (blocks 128..639) =================
__global__ __launch_bounds__(1024) void tl_prep(const float* __restrict__ emb,
                                                const int* __restrict__ labels,
                                                unsigned short* __restrict__ F,
                                                float* __restrict__ dapA) {
    __shared__ float Lrow[MAXM][DIM + 4];
    __shared__ unsigned int minU[MAXM];
    __shared__ float linv[MAXM];
    __shared__ int   lidx[MAXM];
    __shared__ int   lcnt;

    const int blk = blockIdx.x;
    const int tid = threadIdx.x;

    if (blk < BATCH / 64) {
        // ---- prep path: 64 rows/block, 16 threads/row (seg = k/8), fragment-order 16B stores ----
        int rloc = tid >> 4;
        int seg  = tid & 15;           // 8-element k-segment 0..15
        int row  = blk * 64 + rloc;
        const float4* p = reinterpret_cast<const float4*>(emb + (size_t)row * DIM);
        float4 a = p[seg * 2], b = p[seg * 2 + 1];
        float ss = a.x*a.x + a.y*a.y + a.z*a.z + a.w*a.w
                 + b.x*b.x + b.y*b.y + b.z*b.z + b.w*b.w;
#pragma unroll
        for (int o = 1; o < 16; o <<= 1) ss += __shfl_xor(ss, o);
        float inv = 1.0f / fmaxf(sqrtf(ss), 1e-12f);
        f16x8 h;
        h[0]=(_Float16)(a.x*inv); h[1]=(_Float16)(a.y*inv);
        h[2]=(_Float16)(a.z*inv); h[3]=(_Float16)(a.w*inv);
        h[4]=(_Float16)(b.x*inv); h[5]=(_Float16)(b.y*inv);
        h[6]=(_Float16)(b.z*inv); h[7]=(_Float16)(b.w*inv);
        int kc = seg >> 2, g = seg & 3;
        size_t off = (size_t)(row >> 4) * 4096 + kc * 1024 + g * 256 + (row & 15) * 16;
        *reinterpret_cast<f16x8*>((char*)F + off) = h;
        return;
    }

    // ---- class path: hardest positive for every member of class c ----
    const int c = blk - BATCH / 64;
    if (tid == 0) lcnt = 0;
    if (tid < MAXM) minU[tid] = 0xFFFFFFFFu;
    __syncthreads();

#pragma unroll
    for (int k = 0; k < BATCH / 1024; ++k) {      // 8 iterations
        int idx = tid + k * 1024;
        if (labels[idx] == c) {
            int p = atomicAdd(&lcnt, 1);
            if (p < MAXM) lidx[p] = idx;
        }
    }
    __syncthreads();
    const int cnt = min(lcnt, MAXM);

    // stage member rows (16 threads per member: 2 float4 each) + inverse norms
    {
        int m = tid >> 4, q = tid & 15;
        float ss = 0.0f;
        if (m < cnt) {
            const float4* src = reinterpret_cast<const float4*>(emb + (size_t)lidx[m] * DIM) + q * 2;
            float4 v0 = src[0], v1 = src[1];
            *reinterpret_cast<float4*>(&Lrow[m][q * 8])     = v0;
            *reinterpret_cast<float4*>(&Lrow[m][q * 8 + 4]) = v1;
            ss = v0.x*v0.x + v0.y*v0.y + v0.z*v0.z + v0.w*v0.w
               + v1.x*v1.x + v1.y*v1.y + v1.z*v1.z + v1.w*v1.w;
        }
#pragma unroll
        for (int o = 1; o < 16; o <<= 1) ss += __shfl_xor(ss, o);
        if (m < cnt && q == 0) linv[m] = 1.0f / fmaxf(sqrtf(ss), 1e-12f);
    }
    __syncthreads();

    // all-pairs min dot per member (min order-invariant -> deterministic)
    const int P = cnt * cnt;
    for (int p = tid; p < P; p += 1024) {
        int i = p / cnt, j = p - i * cnt;
        if (i != j) {
            const float4* ra = reinterpret_cast<const float4*>(&Lrow[i][0]);
            const float4* rb = reinterpret_cast<const float4*>(&Lrow[j][0]);
            float acc = 0.0f;
#pragma unroll
            for (int u8 = 0; u8 < 32; ++u8) {
                float4 a = ra[u8], b = rb[u8];
                acc += a.x*b.x + a.y*b.y + a.z*b.z + a.w*b.w;
            }
            float dm = acc * linv[i] * linv[j];
            unsigned u   = __float_as_uint(dm);
            unsigned key = (u >> 31) ? ~u : (u | 0x80000000u);
            atomicMin(&minU[i], key);
        }
    }
    __syncthreads();

    if (tid < cnt) {
        float dap = -INFINITY;
        if (cnt >= 2) {
            unsigned key = minU[tid];
            unsigned u   = (key & 0x80000000u) ? (key & 0x7FFFFFFFu) : ~key;
            float md = __uint_as_float(u);
            dap = fmaxf(1.0f - md, 0.0f);
        }
        dapA[lidx[tid]] = dap;
    }
}

// ================= K2: barrier-free fragment-stream MFMA mining =================
__global__ __launch_bounds__(256, 4) void tl_mine(const unsigned short* __restrict__ Fm,
                                                  const int* __restrict__ labels,
                                                  const float* __restrict__ dapA,
                                                  float* __restrict__ part) {
    __shared__ int   Ls[CHW];        // 4 KB chunk labels
    __shared__ float mkS[2][64];

    const int tid = threadIdx.x;
    const int l   = tid & 63;
    const int wid = tid >> 6;
    const int wr  = wid >> 1, wc = wid & 1;   // 2x2 wave grid; wave tile 32 rows x 32 cols
    const int rb  = blockIdx.x >> 3;
    const int ch  = blockIdx.x & (NCHUNK - 1);
    const int rowBase = rb * 64;
    const int colBase = ch * CHW;
    const char* F = (const char*)Fm;

    const int lo   = l & 15;
    const int kgrp = l >> 4;

    // stage chunk labels once (wave-uniform LDS dest; HW adds lane*16)
    __builtin_amdgcn_global_load_lds(
        (const __attribute__((address_space(1))) unsigned int*)(labels + colBase + wid * 256 + l * 4),
        (__attribute__((address_space(3))) unsigned int*)((char*)Ls + wid * 1024),
        16, 0, 0);

    // A fragments: 2 row-groups x 4 kc, each one coalesced 1KB wave-load
    const int ctA = (rowBase >> 4) + wr * 2;
    f16x8 af[2][4];
#pragma unroll
    for (int rf = 0; rf < 2; ++rf)
#pragma unroll
        for (int kc = 0; kc < 4; ++kc)
            af[rf][kc] = *reinterpret_cast<const f16x8*>(
                F + (size_t)(ctA + rf) * 4096 + kc * 1024 + l * 16);

    // per-row mining state (C/D: col=lane&15, row=(lane>>4)*4+reg)
    float wCen[8]; int la[8]; float mk[8];
#pragma unroll
    for (int rf = 0; rf < 2; ++rf)
#pragma unroll
        for (int i = 0; i < 4; ++i) {
            int r = rowBase + wr * 32 + rf * 16 + kgrp * 4 + i;
            float draw = dapA[r];
            float ds   = (draw > -1e30f) ? draw : 0.0f;
            wCen[rf * 4 + i] = (1.0f - ds) - 0.5f * MARGIN_F;
            la[rf * 4 + i]   = labels[r];
            mk[rf * 4 + i]   = -INFINITY;
        }
    __syncthreads();   // labels staged; only barrier before the part-write

    const int ctC0 = (colBase >> 4) + wc * 2;   // first col-group for this wave at step 0
    for (int t = 0; t < NT; ++t) {
        // 8 coalesced fragment loads (independent -> deep pipelining via TLP/ILP)
        f16x8 bf[2][4];
#pragma unroll
        for (int cf = 0; cf < 2; ++cf)
#pragma unroll
            for (int kc = 0; kc < 4; ++kc)
                bf[cf][kc] = *reinterpret_cast<const f16x8*>(
                    F + (size_t)(ctC0 + t * 4 + cf) * 4096 + kc * 1024 + l * 16);

        int lbB[2];
#pragma unroll
        for (int cf = 0; cf < 2; ++cf)
            lbB[cf] = Ls[t * ST + wc * 32 + cf * 16 + lo];

        f32x4 acc[2][2];
#pragma unroll
        for (int rf = 0; rf < 2; ++rf)
#pragma unroll
            for (int cf = 0; cf < 2; ++cf) {
                acc[rf][cf][0] = 0.0f; acc[rf][cf][1] = 0.0f;
                acc[rf][cf][2] = 0.0f; acc[rf][cf][3] = 0.0f;
            }

#pragma unroll
        for (int kc = 0; kc < 4; ++kc)
#pragma unroll
            for (int rf = 0; rf < 2; ++rf)
#pragma unroll
                for (int cf = 0; cf < 2; ++cf)
                    acc[rf][cf] = __builtin_amdgcn_mfma_f32_16x16x32_f16(
                        af[rf][kc], bf[cf][kc], acc[rf][cf], 0, 0, 0);

        // fused mining epilogue (dot space, single key)
#pragma unroll
        for (int rf = 0; rf < 2; ++rf)
#pragma unroll
            for (int i = 0; i < 4; ++i) {
                int ri = rf * 4 + i;
                float cen = wCen[ri];
                int   lr  = la[ri];
                float d0  = acc[rf][0][i];
                float d1  = acc[rf][1][i];
                bool  w0  = fabsf(d0 - cen) < (0.5f * MARGIN_F);
                bool  w1  = fabsf(d1 - cen) < (0.5f * MARGIN_F);
                float k0  = w0 ? d0 : d0 - 4.0f;
                float k1  = w1 ? d1 : d1 - 4.0f;
                k0 = (lbB[0] != lr) ? k0 : -INFINITY;
                k1 = (lbB[1] != lr) ? k1 : -INFINITY;
                mk[ri] = fmaxf(mk[ri], fmaxf(k0, k1));   // -> v_max3_f32
            }
    }

    // reduce across the 16 lanes sharing rows (lane bits 0..3)
#pragma unroll
    for (int m = 1; m < 16; m <<= 1)
#pragma unroll
        for (int r8 = 0; r8 < 8; ++r8)
            mk[r8] = fmaxf(mk[r8], __shfl_xor(mk[r8], m));
    if (lo == 0) {
#pragma unroll
        for (int rf = 0; rf < 2; ++rf)
#pragma unroll
            for (int i = 0; i < 4; ++i)
                mkS[wc][wr * 32 + rf * 16 + kgrp * 4 + i] = mk[rf * 4 + i];
    }
    __syncthreads();
    if (tid < 64)
        part[(size_t)ch * BATCH + rowBase + tid] = fmaxf(mkS[0][tid], mkS[1][tid]);
}

// ================= K3: finalize (separate launch; stream order provides visibility) =================
__global__ __launch_bounds__(1024) void tl_fin(const float* __restrict__ dapA,
                                               const float* __restrict__ part,
                                               float* __restrict__ out) {
    int tid = threadIdx.x;
    float s = 0.0f, cc = 0.0f;
    for (int r = tid; r < BATCH; r += 1024) {
        float draw = dapA[r];
        float mkv  = part[r];
#pragma unroll
        for (int chh = 1; chh < NCHUNK; ++chh)
            mkv = fmaxf(mkv, part[(size_t)chh * BATCH + r]);
        bool hasPos = draw > -1e30f;
        bool hasNeg = mkv  > -1e30f;
        float dapv  = hasPos ? draw : 0.0f;
        bool  semi  = mkv > -2.0f;                 // window keys > -1.3; shifted keys < -2.9
        float dotAn = semi ? mkv : mkv + 4.0f;
        float dan   = fmaxf(1.0f - dotAn, 0.0f);
        if (hasPos && hasNeg) {
            s  += fmaxf(dapv - dan + MARGIN_F, 0.0f);
            cc += 1.0f;
        }
    }
#pragma unroll
    for (int o = 32; o > 0; o >>= 1) { s += __shfl_xor(s, o); cc += __shfl_xor(cc, o); }
    __shared__ float ssum[16], scnt[16];
    int w = tid >> 6;
    if ((tid & 63) == 0) { ssum[w] = s; scnt[w] = cc; }
    __syncthreads();
    if (tid == 0) {
        float S = 0.0f, C = 0.0f;
#pragma unroll
        for (int i = 0; i < 16; ++i) { S += ssum[i]; C += scnt[i]; }
        out[0] = S / fmaxf(C, 1.0f);
    }
}

extern "C" void kernel_launch(void* const* d_in, const int* in_sizes, int n_in,
                              void* d_out, int out_size, void* d_ws, size_t ws_size,
                              hipStream_t stream) {
    const float* emb    = (const float*)d_in[0];
    const int*   labels = (const int*)d_in[1];
    float*       out    = (float*)d_out;

    char* ws = (char*)d_ws;
    unsigned short* F    = (unsigned short*)(ws);                          // 2 MB fragment-packed
    float*        dapA   = (float*)(ws + 2 * 1024 * 1024);                 // 32 KB
    float*        part   = (float*)(ws + 2 * 1024 * 1024 + 64 * 1024);     // 256 KB

    tl_prep<<<BATCH / 64 + NCLS, 1024, 0, stream>>>(emb, labels, F, dapA);
    tl_mine<<<NBLK2, 256, 0, stream>>>(F, labels, dapA, part);
    tl_fin <<<1, 1024, 0, stream>>>(dapA, part, out);
}